// Round 5
// baseline (5684.112 us; speedup 1.0000x reference)
//
#include <hip/hip_runtime.h>

#define TT 2000
#define NN 512
#define MM 64
#define ALPHA 0.2f   // DT/TAU

typedef unsigned long long u64;

// DPP row_ror butterfly reduce within 16-lane rows (VALU pipe, not LDS).
// Rotate-and-add by 1,2,4,8: EVERY lane of the row ends with the 16-lane sum.
#define DPP_ROR_ADD(v, ctrl) do { \
  int _t = __builtin_amdgcn_update_dpp(0, __float_as_int(v), (ctrl), 0xF, 0xF, true); \
  (v) += __int_as_float(_t); } while (0)
#define ROW_REDUCE16(v) do { \
  DPP_ROR_ADD(v, 0x121); DPP_ROR_ADD(v, 0x122); \
  DPP_ROR_ADD(v, 0x124); DPP_ROR_ADD(v, 0x128); } while (0)

__device__ __forceinline__ float hsum4(float4 a){ return (a.x + a.y) + (a.z + a.w); }

// 256 blocks (1/CU, co-resident): bid = p*64 + r; block owns neurons
// [p*128, p*128+128) of batch row r. 512 thr: group g = tid>>4 owns 4 neurons,
// l16 = tid&15 owns K-chunks {jj*64 + l16*4 .. +3 : jj=0..7}  (stride 64 = 16
// lanes x 4 floats; round-2's jj*128 stride was the correctness bug).
// Weights: 32 float4 = 128 VGPR/thread -> register-resident. One __syncthreads
// per step; cross-block u exchange via tagged 8B relaxed agent-scope packets.
__global__ __launch_bounds__(512, 2) void ctrnn(
    const float* __restrict__ I, const float* __restrict__ x0,
    const float* __restrict__ W_in, const float* __restrict__ W_rec,
    const float* __restrict__ b, const float* __restrict__ W_out,
    float* __restrict__ out_x, float* __restrict__ out_u, float* __restrict__ out_y,
    u64* __restrict__ pkt)
{
  __shared__ float u_lds[2][16 * 36];     // u[k] at (k>>5)*36 + (k&31); parity-buffered
  __shared__ float xbuf[2][128 * 9];      // octet-parity staging, stride-9 pad
  __shared__ float ubuf[2][128 * 9];

  const int p = blockIdx.x >> 6, r = blockIdx.x & 63;
  const int tid = threadIdx.x;
  const int wave = tid >> 6, lane = tid & 63;
  const int g = tid >> 4, l16 = tid & 15;
  const int nb = p * 128 + g * 4;

  // ---- weights into registers, coalesced (16 lanes x 16B = 256B/row-pass) ----
  float4 w[4][8];
  #pragma unroll
  for (int rr = 0; rr < 4; rr++)
    #pragma unroll
    for (int jj = 0; jj < 8; jj++)
      w[rr][jj] = *(const float4*)(W_rec + (size_t)(nb + rr) * NN + jj * 64 + l16 * 4);

  const bool owner = (l16 == 0);          // updates neurons nb..nb+3
  float wi0[4], wi1[4], bb[4], xs[4], us[4];
  const float x00 = x0[0];
  const float u00 = tanhf(x00);
  #pragma unroll
  for (int j = 0; j < 4; j++){ xs[j] = x00; us[j] = u00; wi0[j] = wi1[j] = bb[j] = 0.f; }
  if (owner){
    #pragma unroll
    for (int j = 0; j < 4; j++){
      wi0[j] = W_in[2 * (nb + j)]; wi1[j] = W_in[2 * (nb + j) + 1]; bb[j] = b[nb + j];
    }
  }

  const bool yth = (p == 0) && (wave < 2) && (lane < 16);   // wave w -> channel w
  float4 wy[8];
  if (yth){
    #pragma unroll
    for (int c = 0; c < 8; c++)
      wy[c] = *(const float4*)(W_out + wave * NN + lane * 32 + 4 * c);
  }
  float yh0=0,yh1=0,yh2=0,yh3=0,yh4=0,yh5=0,yh6=0,yh7=0;

  u_lds[0][(tid >> 5) * 36 + (tid & 31)] = u00;   // u_0, buffer 0
  __syncthreads();

  const float* Ib = I + (size_t)r * 2 * TT;
  float* ox = out_x + (size_t)r * NN * TT;
  float* ou = out_u + (size_t)r * NN * TT;
  float* oy = out_y + (size_t)r * 2 * TT;
  u64* pr = pkt + (size_t)r * NN;
  const int q  = tid - 128;                                  // poller id
  const int rn = (q < p * 128) ? q : q + 128;                // remote neuron (q>=0)

  for (int t = 0; t < TT; t++){
    const int cbuf = t & 1, nbuf = cbuf ^ 1;
    const int oct = (t >> 3) & 1, p8 = t & 7;

    // 0. early input loads (latency hidden under matvec)
    float i0 = 0.f, i1 = 0.f;
    if (owner){ i0 = Ib[t]; i1 = Ib[TT + t]; }

    // 1. stage pre-step x,u
    if (owner){
      #pragma unroll
      for (int j = 0; j < 4; j++){
        xbuf[oct][(g * 4 + j) * 9 + p8] = xs[j];
        ubuf[oct][(g * 4 + j) * 9 + p8] = us[j];
      }
    }

    // 2. y_{t-1} = W_out . u_t ; rolling 8-deep history in regs, lane0 flushes
    if (yth){
      const float* ub = u_lds[cbuf] + lane * 36;
      float4 acc = make_float4(0,0,0,0);
      #pragma unroll
      for (int c = 0; c < 8; c++){
        float4 uv = *(const float4*)(ub + 4 * c);
        acc.x = fmaf(wy[c].x, uv.x, acc.x); acc.y = fmaf(wy[c].y, uv.y, acc.y);
        acc.z = fmaf(wy[c].z, uv.z, acc.z); acc.w = fmaf(wy[c].w, uv.w, acc.w);
      }
      float yv = hsum4(acc);
      ROW_REDUCE16(yv);
      yh0=yh1; yh1=yh2; yh2=yh3; yh3=yh4; yh4=yh5; yh5=yh6; yh6=yh7; yh7=yv;
      if (lane == 0 && p8 == 0 && t > 0){
        float* dst = oy + (size_t)wave * TT + (t - 8);
        *(float4*)dst       = make_float4(yh0, yh1, yh2, yh3);
        *(float4*)(dst + 4) = make_float4(yh4, yh5, yh6, yh7);
      }
    }

    // 3. main matvec: 4 neurons x 32 k per thread over u_t
    //    k = jj*64 + l16*4 + c  ->  u_lds row jj*2 + (l16>>3), col (l16&7)*4
    float s[4];
    {
      const float* ub = u_lds[cbuf];
      float4 a0 = make_float4(0,0,0,0), a1 = a0, a2 = a0, a3 = a0;
      #pragma unroll
      for (int jj = 0; jj < 8; jj++){
        float4 uv = *(const float4*)(ub + (jj * 2 + (l16 >> 3)) * 36 + (l16 & 7) * 4);
        a0.x = fmaf(w[0][jj].x, uv.x, a0.x); a0.y = fmaf(w[0][jj].y, uv.y, a0.y);
        a0.z = fmaf(w[0][jj].z, uv.z, a0.z); a0.w = fmaf(w[0][jj].w, uv.w, a0.w);
        a1.x = fmaf(w[1][jj].x, uv.x, a1.x); a1.y = fmaf(w[1][jj].y, uv.y, a1.y);
        a1.z = fmaf(w[1][jj].z, uv.z, a1.z); a1.w = fmaf(w[1][jj].w, uv.w, a1.w);
        a2.x = fmaf(w[2][jj].x, uv.x, a2.x); a2.y = fmaf(w[2][jj].y, uv.y, a2.y);
        a2.z = fmaf(w[2][jj].z, uv.z, a2.z); a2.w = fmaf(w[2][jj].w, uv.w, a2.w);
        a3.x = fmaf(w[3][jj].x, uv.x, a3.x); a3.y = fmaf(w[3][jj].y, uv.y, a3.y);
        a3.z = fmaf(w[3][jj].z, uv.z, a3.z); a3.w = fmaf(w[3][jj].w, uv.w, a3.w);
      }
      s[0] = hsum4(a0); s[1] = hsum4(a1); s[2] = hsum4(a2); s[3] = hsum4(a3);
      ROW_REDUCE16(s[0]); ROW_REDUCE16(s[1]); ROW_REDUCE16(s[2]); ROW_REDUCE16(s[3]);
    }

    // 4. owner: Euler update, tanh, publish u_{t+1} (LDS + tagged packets)
    if (owner){
      #pragma unroll
      for (int j = 0; j < 4; j++){
        float pre = s[j] + fmaf(wi0[j], i0, fmaf(wi1[j], i1, bb[j]));
        xs[j] = fmaf(ALPHA, pre - xs[j], xs[j]);     // x + a*(pre-x)
        us[j] = tanhf(xs[j]);
      }
      *(float4*)(u_lds[nbuf] + (nb >> 5) * 36 + (nb & 31)) =
          make_float4(us[0], us[1], us[2], us[3]);
      const u64 tagw = ((u64)(unsigned)(t + 1)) << 32;
      u64* pd = pr + (size_t)nbuf * (MM * NN) + nb;
      #pragma unroll
      for (int j = 0; j < 4; j++)
        __hip_atomic_store(pd + j, tagw | (u64)__float_as_uint(us[j]),
                           __ATOMIC_RELAXED, __HIP_MEMORY_SCOPE_AGENT);
    }
    asm volatile("" ::: "memory");   // pin store-before-poll (deadlock safety)

    // 5. pollers: gather remote u_{t+1}
    if (q >= 0){
      u64* ps = pr + (size_t)nbuf * (MM * NN) + rn;
      u64 pk = __hip_atomic_load(ps, __ATOMIC_RELAXED, __HIP_MEMORY_SCOPE_AGENT);
      while ((unsigned)(pk >> 32) != (unsigned)(t + 1)){
        __builtin_amdgcn_s_sleep(1);
        pk = __hip_atomic_load(ps, __ATOMIC_RELAXED, __HIP_MEMORY_SCOPE_AGENT);
      }
      u_lds[nbuf][(rn >> 5) * 36 + (rn & 31)] = __uint_as_float((unsigned)pk);
    }

    // 6. flush previous x,u octet (coalesced float4, separated by 8 barriers)
    if (p8 == 0 && t > 0){
      const int arr = tid >> 8, n2 = (tid >> 1) & 127, h = tid & 1;
      const float* src = (arr ? ubuf[oct ^ 1] : xbuf[oct ^ 1]) + n2 * 9 + 4 * h;
      float* dst = (arr ? ou : ox) + (size_t)(p * 128 + n2) * TT + (t - 8) + 4 * h;
      *(float4*)dst = make_float4(src[0], src[1], src[2], src[3]);
    }

    __syncthreads();   // single barrier: u_{t+1} visible for next matvec
  }

  // ---- epilogue: y_1999 from u_2000 (buffer 0), final y + x/u flushes ----
  if (yth){
    const float* ub = u_lds[0] + lane * 36;
    float4 acc = make_float4(0,0,0,0);
    #pragma unroll
    for (int c = 0; c < 8; c++){
      float4 uv = *(const float4*)(ub + 4 * c);
      acc.x = fmaf(wy[c].x, uv.x, acc.x); acc.y = fmaf(wy[c].y, uv.y, acc.y);
      acc.z = fmaf(wy[c].z, uv.z, acc.z); acc.w = fmaf(wy[c].w, uv.w, acc.w);
    }
    float yv = hsum4(acc);
    ROW_REDUCE16(yv);
    yh0=yh1; yh1=yh2; yh2=yh3; yh3=yh4; yh4=yh5; yh5=yh6; yh6=yh7; yh7=yv;
    if (lane == 0){
      float* dst = oy + (size_t)wave * TT + (TT - 8);
      *(float4*)dst       = make_float4(yh0, yh1, yh2, yh3);
      *(float4*)(dst + 4) = make_float4(yh4, yh5, yh6, yh7);
    }
  }
  {
    const int arr = tid >> 8, n2 = (tid >> 1) & 127, h = tid & 1;
    const float* src = (arr ? ubuf[1] : xbuf[1]) + n2 * 9 + 4 * h;
    float* dst = (arr ? ou : ox) + (size_t)(p * 128 + n2) * TT + (TT - 8) + 4 * h;
    *(float4*)dst = make_float4(src[0], src[1], src[2], src[3]);
  }
}

extern "C" void kernel_launch(void* const* d_in, const int* in_sizes, int n_in,
                              void* d_out, int out_size, void* d_ws, size_t ws_size,
                              hipStream_t stream){
  const float* I     = (const float*)d_in[0];
  const float* x0    = (const float*)d_in[1];
  const float* W_in  = (const float*)d_in[2];
  const float* W_rec = (const float*)d_in[3];
  const float* b     = (const float*)d_in[4];
  const float* W_out = (const float*)d_in[5];

  float* out_x = (float*)d_out;
  float* out_u = out_x + (size_t)MM * NN * TT;
  float* out_y = out_u + (size_t)MM * NN * TT;
  u64*   pkt   = (u64*)d_ws;   // 2*64*512*8B = 512 KB; 0xAA poison never matches tags

  ctrnn<<<MM * 4, 512, 0, stream>>>(I, x0, W_in, W_rec, b, W_out,
                                    out_x, out_u, out_y, pkt);
}